// Round 3
// baseline (528.180 us; speedup 1.0000x reference)
//
#include <hip/hip_runtime.h>
#include <hip/hip_bf16.h>
#include <stdint.h>

// GroupedQAttention on MI355X.
// cast x->bf16, transpose-cast weights -> bf16 BT,
// GEMM1 (256^2 4-phase read-pipelined bf16 MFMA) -> qkvw,
// fused tiny-attention*w -> ow (bf16), GEMM2 (same) -> fp32 out.

typedef __bf16 bf16;
typedef __bf16 bf16x8 __attribute__((ext_vector_type(8)));
typedef float f32x4 __attribute__((ext_vector_type(4)));

__device__ __forceinline__ void gload16(const bf16* g, bf16* l) {
  __builtin_amdgcn_global_load_lds(
      (const __attribute__((address_space(1))) void*)g,
      (__attribute__((address_space(3))) void*)l, 16, 0, 0);
}

__device__ __forceinline__ void nt_store(bf16 v, bf16* p) {
  union { bf16 h; short s; } u; u.h = v;
  __builtin_nontemporal_store(u.s, (short*)p);
}
__device__ __forceinline__ void nt_store(float v, float* p) {
  __builtin_nontemporal_store(v, p);
}

#define BAR() asm volatile("s_barrier" ::: "memory")
#define SB() __builtin_amdgcn_sched_barrier(0)
#define LGKM0 asm volatile("s_waitcnt lgkmcnt(0)" ::: "memory")
#define PRIO1 __builtin_amdgcn_s_setprio(1)
#define PRIO0 __builtin_amdgcn_s_setprio(0)

// ---------- 256x256-tile GEMM: C[M][N] = A[M][1024] * BT[N][1024]^T ----------
// 512 threads = 8 waves (2Mx4N). BK=64, 16 K-tiles. LDS 128KiB double-buffered.
// Swizzle involution on [128][64]bf16 halves: byte ^= ((byte>>7)&7)<<4.
// Schedule per tile (1 barrier/phase, reads pipelined one phase ahead):
//  ph0: stage A(T+1)x4 | BAR lgkm0 | read B1 | MFMA(0,0)
//  ph1:                | BAR lgkm0 |         | MFMA(0,1) | read A1
//  ph2:                | BAR lgkm0 |         | MFMA(1,1)
//  ph3: stage B(T+2)x4, vmcnt(4) | BAR lgkm0 | MFMA(1,0) | read A0,B0 (T+1)
#define READ_A(mq, AO)                                                        \
  {                                                                           \
    _Pragma("unroll") for (int i = 0; i < 4; ++i)                             \
        _Pragma("unroll") for (int kk = 0; kk < 2; ++kk)                      \
            a[i][kk] = *(const bf16x8*)(lds + (AO) +                          \
                                        ((mq)*64 + i * 16 + fr) * 128 +       \
                                        ((kk * 64 + fkb) ^ xo));              \
  }
#define READ_B(nh, BO)                                                        \
  {                                                                           \
    _Pragma("unroll") for (int j = 0; j < 2; ++j)                             \
        _Pragma("unroll") for (int kk = 0; kk < 2; ++kk)                      \
            b[(nh)*2 + j][kk] = *(const bf16x8*)(lds + (BO) +                 \
                                                 (bro + (nh)*32 + j * 16 + fr) * 128 + \
                                                 ((kk * 64 + fkb) ^ xo));     \
  }
#define MFMA_Q(mq, nh)                                                        \
  {                                                                           \
    _Pragma("unroll") for (int i = 0; i < 4; ++i)                             \
        _Pragma("unroll") for (int j = 0; j < 2; ++j) {                       \
      acc[(mq)*4 + i][(nh)*2 + j] = __builtin_amdgcn_mfma_f32_16x16x32_bf16(  \
          a[i][0], b[(nh)*2 + j][0], acc[(mq)*4 + i][(nh)*2 + j], 0, 0, 0);   \
      acc[(mq)*4 + i][(nh)*2 + j] = __builtin_amdgcn_mfma_f32_16x16x32_bf16(  \
          a[i][1], b[(nh)*2 + j][1], acc[(mq)*4 + i][(nh)*2 + j], 0, 0, 0);   \
    }                                                                         \
  }
#define STAGE_A(h, X)                                                         \
  {                                                                           \
    const int ro = ((X)&1) * 65536 + (h)*16384;                               \
    const bf16* g = gA + ((h)*128) * 1024 + (X)*64;                           \
    gload16(g, (bf16*)(lds + ro + wv * 1024));                                \
    gload16(g + 64 * 1024, (bf16*)(lds + ro + 8192 + wv * 1024));             \
  }
#define STAGE_B(h, X)                                                         \
  {                                                                           \
    const int ro = ((X)&1) * 65536 + 32768 + (h)*16384;                       \
    const bf16* g = gB + ((h)*128) * 1024 + (X)*64;                           \
    gload16(g, (bf16*)(lds + ro + wv * 1024));                                \
    gload16(g + 64 * 1024, (bf16*)(lds + ro + 8192 + wv * 1024));             \
  }

template <typename OutT>
__global__ __launch_bounds__(512, 2)
void gemm256(const bf16* __restrict__ A, const bf16* __restrict__ BT,
             OutT* __restrict__ C, int N) {
  constexpr int K = 1024;
  __shared__ __align__(16) char smem[131072];
  char* lds = smem;

  const int tid = threadIdx.x;
  const int lane = tid & 63;
  const int wv = tid >> 6;
  const int wr = wv >> 2;  // 0..1
  const int wc = wv & 3;   // 0..3

  // bijective XCD swizzle, col-major tile order (B-panel stays L2-resident)
  const int gy = gridDim.y;
  const int nwg = gridDim.x * gy;
  const int bid = blockIdx.y * gridDim.x + blockIdx.x;
  const int swz = (bid & 7) * (nwg >> 3) + (bid >> 3);
  const long col0 = (long)(swz / gy) * 256;
  const long row0 = (long)(swz % gy) * 256;

  // staging source (pre-swizzled so linear global_load_lds dest == swizzled layout)
  const int srow = tid >> 3;  // 0..63
  const int scol = (((tid & 7) * 16) ^ ((srow & 7) << 4)) >> 1;  // elements
  const bf16* gA = A + (row0 + srow) * K + scol;
  const bf16* gB = BT + (col0 + srow) * K + scol;

  // fragment read addressing
  const int fr = lane & 15;
  const int fkb = (lane >> 4) * 16;  // byte offset of k-slice
  const int xo = (fr & 7) << 4;
  const int bro = (wc & 1) * 64;

  bf16x8 a[4][2], b[4][2];
  f32x4 acc[8][4] = {};

  // prologue: tile0 (4 half-tiles) + B(1) (2 half-tiles); keep B(1) in flight
  STAGE_A(0, 0); STAGE_A(1, 0); STAGE_B(0, 0); STAGE_B(1, 0);
  STAGE_B(0, 1); STAGE_B(1, 1);
  asm volatile("s_waitcnt vmcnt(4)" ::: "memory");
  SB(); BAR(); SB();
  {
    const int aoff0 = wr * 16384;
    const int boff0 = 32768 + (wc >> 1) * 16384;
    READ_A(0, aoff0); READ_B(0, boff0);
  }
  SB();

  for (int T = 0; T < 16; ++T) {
    const int d = T & 1;
    const int aoff = d * 65536 + wr * 16384;
    const int boff = d * 65536 + 32768 + (wc >> 1) * 16384;
    const int aoffN = (d ^ 1) * 65536 + wr * 16384;
    const int boffN = (d ^ 1) * 65536 + 32768 + (wc >> 1) * 16384;
    // ph0
    if (T < 15) { STAGE_A(0, T + 1); STAGE_A(1, T + 1); }
    SB(); BAR(); LGKM0; SB();
    READ_B(1, boff); SB();
    PRIO1; MFMA_Q(0, 0); PRIO0; SB();
    // ph1
    BAR(); LGKM0; SB();
    PRIO1; MFMA_Q(0, 1); PRIO0; SB();
    READ_A(1, aoff); SB();
    // ph2
    BAR(); LGKM0; SB();
    PRIO1; MFMA_Q(1, 1); PRIO0; SB();
    // ph3
    if (T < 14) {
      STAGE_B(0, T + 2); STAGE_B(1, T + 2);
      asm volatile("s_waitcnt vmcnt(4)" ::: "memory");
    } else if (T == 14) {
      asm volatile("s_waitcnt vmcnt(0)" ::: "memory");
    }
    SB(); BAR(); LGKM0; SB();
    PRIO1; MFMA_Q(1, 0); PRIO0; SB();
    if (T < 15) { READ_A(0, aoffN); READ_B(0, boffN); }
    SB();
  }

  // epilogue: C/D layout col=lane&15, row=(lane>>4)*4+reg; non-temporal stores
  const int crow = (lane >> 4) * 4;
  const int ccol = lane & 15;
  const long rb = row0 + wr * 128;
  const long cb = col0 + wc * 64;
#pragma unroll
  for (int m = 0; m < 8; ++m)
#pragma unroll
    for (int n = 0; n < 4; ++n)
#pragma unroll
      for (int i = 0; i < 4; ++i)
        nt_store((OutT)acc[m][n][i],
                 &C[(rb + m * 16 + crow + i) * (long)N + cb + n * 16 + ccol]);
}

// ---------------- fused tiny attention ----------------
__device__ __forceinline__ void load16f(const bf16* p, float* f) {
  const uint4* u = (const uint4*)p;
  uint4 a = u[0], b = u[1];
  uint32_t w[8] = {a.x, a.y, a.z, a.w, b.x, b.y, b.z, b.w};
#pragma unroll
  for (int j = 0; j < 8; ++j) {
    f[2 * j] = __uint_as_float(w[j] << 16);
    f[2 * j + 1] = __uint_as_float(w[j] & 0xffff0000u);
  }
}

// block = (s_hi, g, bz); 256 threads = 16 s_lo x 16 h1
__global__ __launch_bounds__(256)
void attn_fuse(const bf16* __restrict__ qkvw, bf16* __restrict__ ow,
               int b0, long bstride) {
  __shared__ bf16 data[16 * 1024];
  const int s_hi = blockIdx.x;
  const int g = blockIdx.y;
  const int bz = blockIdx.z;
  const int b = b0 + bz;
  const bf16* base = qkvw + (long)bz * bstride;
  const int tid = threadIdx.x;

#pragma unroll
  for (int i = 0; i < 8; ++i) {
    int c = tid + i * 256;
    int h = c >> 7;
    int col = (c & 127) * 8;
    *(uint4*)&data[h * 1024 + col] =
        *(const uint4*)(base + (long)(h * 256 + s_hi) * 4096 + g * 1024 + col);
  }
  __syncthreads();

  const int s_lo = tid >> 4;
  const int h1 = tid & 15;
  const int off = s_lo * 16;

  float q[16], p[16], o[16];
  load16f(&data[h1 * 1024 + off], q);

  float mx = -1e30f;
#pragma unroll
  for (int h2 = 0; h2 < 16; ++h2) {
    float kf[16];
    load16f(&data[h2 * 1024 + 256 + off], kf);
    float s = 0.f;
#pragma unroll
    for (int d = 0; d < 16; ++d) s += q[d] * kf[d];
    s *= 0.25f;  // HD^-0.5, HD=16
    p[h2] = s;
    mx = fmaxf(mx, s);
  }
  float sum = 0.f;
#pragma unroll
  for (int h2 = 0; h2 < 16; ++h2) {
    float e = __expf(p[h2] - mx);
    p[h2] = e;
    sum += e;
  }
  const float inv = 1.f / sum;
#pragma unroll
  for (int d = 0; d < 16; ++d) o[d] = 0.f;
#pragma unroll
  for (int h2 = 0; h2 < 16; ++h2) {
    float vf[16];
    load16f(&data[h2 * 1024 + 512 + off], vf);
    const float av = p[h2] * inv;
#pragma unroll
    for (int d = 0; d < 16; ++d) o[d] += av * vf[d];
  }
  float wf[16];
  load16f(&data[h1 * 1024 + 768 + off], wf);

  const int bp = g * 8 + b;  // concat index along axis 0
  const long R = (long)(bp >> 2) * 4096 + (bp & 3) * 1024 + h1 * 64 + (s_hi >> 2);
  const int cbo = (s_hi & 3) * 256 + off;
  union { uint4 u[2]; bf16 hh[16]; } st;
#pragma unroll
  for (int d = 0; d < 16; ++d) st.hh[d] = (bf16)(o[d] * wf[d]);
  uint4* dst = (uint4*)&ow[R * 1024 + cbo];
  dst[0] = st.u[0];
  dst[1] = st.u[1];
}

// ---------------- casts ----------------
__global__ __launch_bounds__(256)
void cast_x_kernel(const float* __restrict__ in, bf16* __restrict__ out, long n4) {
  long i = (long)blockIdx.x * 256 + threadIdx.x;
  if (i >= n4) return;
  float4 v = ((const float4*)in)[i];
  union { uint2 d; bf16 h[4]; } r;
  r.h[0] = (bf16)v.x; r.h[1] = (bf16)v.y; r.h[2] = (bf16)v.z; r.h[3] = (bf16)v.w;
  ((uint2*)out)[i] = r.d;
}

// out[C][R] = bf16(in[R][C])  (transpose-cast, 64x64 tiles)
__global__ __launch_bounds__(256)
void tcast_kernel(const float* __restrict__ in, bf16* __restrict__ out, int R, int C) {
  __shared__ float t[64][65];
  const int c0 = blockIdx.x * 64, r0 = blockIdx.y * 64;
  const int lr = threadIdx.x >> 6;
  const int lc = threadIdx.x & 63;
#pragma unroll
  for (int i = 0; i < 16; ++i)
    t[lr + i * 4][lc] = in[(long)(r0 + lr + i * 4) * C + c0 + lc];
  __syncthreads();
#pragma unroll
  for (int i = 0; i < 16; ++i) {
    int oc = lr + i * 4;
    out[(long)(c0 + oc) * R + r0 + lc] = (bf16)t[lc][oc];
  }
}

// ---------------- launch ----------------
extern "C" void kernel_launch(void* const* d_in, const int* in_sizes, int n_in,
                              void* d_out, int out_size, void* d_ws, size_t ws_size,
                              hipStream_t stream) {
  const float* x = (const float*)d_in[0];
  const float* w_qkvw = (const float*)d_in[1];
  const float* w_out = (const float*)d_in[2];
  float* out = (float*)d_out;

  char* ws = (char*)d_ws;
  size_t off = 0;
  bf16* x_bf = (bf16*)(ws + off); off += (size_t)32768 * 1024 * 2;
  bf16* bt1  = (bf16*)(ws + off); off += (size_t)4096 * 1024 * 2;
  bf16* bt2  = (bf16*)(ws + off); off += (size_t)1024 * 1024 * 2;
  bf16* owb  = (bf16*)(ws + off); off += (size_t)32768 * 1024 * 2;
  bf16* qk   = (bf16*)(ws + off);
  const size_t rem = ws_size > off ? ws_size - off : 0;
  const size_t full_need = (size_t)32768 * 4096 * 2;

  cast_x_kernel<<<32768, 256, 0, stream>>>(x, x_bf, (long)8388608);
  tcast_kernel<<<dim3(64, 16), 256, 0, stream>>>(w_qkvw, bt1, 1024, 4096);
  tcast_kernel<<<dim3(16, 16), 256, 0, stream>>>(w_out, bt2, 1024, 1024);

  if (rem >= full_need) {
    gemm256<bf16><<<dim3(16, 128), 512, 0, stream>>>(x_bf, bt1, qk, 4096);
    attn_fuse<<<dim3(256, 4, 8), 256, 0, stream>>>(qk, owb, 0, (long)4096 * 4096);
  } else {
    for (int b = 0; b < 8; ++b) {
      gemm256<bf16><<<dim3(16, 16), 512, 0, stream>>>(
          x_bf + (size_t)b * 4096 * 1024, bt1, qk, 4096);
      attn_fuse<<<dim3(256, 4, 1), 256, 0, stream>>>(qk, owb, b, 0);
    }
  }
  gemm256<float><<<dim3(4, 128), 512, 0, stream>>>(owb, bt2, out, 1024);
}

// Round 4
// 463.211 us; speedup vs baseline: 1.1403x; 1.1403x over previous
//
#include <hip/hip_runtime.h>
#include <hip/hip_bf16.h>
#include <stdint.h>

// GroupedQAttention on MI355X.
// cast x->bf16, transpose-cast weights -> bf16 BT,
// GEMM1 (256^2 4-phase read-pipelined bf16 MFMA) -> qkvw,
// fused tiny-attention*w -> ow (bf16), GEMM2 (same) -> fp32 out.
// R3 lesson: row-major XCD chunking (M>>N) + plain stores; col-major chunking
// (+240MB FETCH) and nontemporal 2B stores (+160MB WRITE) both regressed.

typedef __bf16 bf16;
typedef __bf16 bf16x8 __attribute__((ext_vector_type(8)));
typedef float f32x4 __attribute__((ext_vector_type(4)));

__device__ __forceinline__ void gload16(const bf16* g, bf16* l) {
  __builtin_amdgcn_global_load_lds(
      (const __attribute__((address_space(1))) void*)g,
      (__attribute__((address_space(3))) void*)l, 16, 0, 0);
}

#define BAR() asm volatile("s_barrier" ::: "memory")
#define SB() __builtin_amdgcn_sched_barrier(0)
#define LGKM0 asm volatile("s_waitcnt lgkmcnt(0)" ::: "memory")
#define PRIO1 __builtin_amdgcn_s_setprio(1)
#define PRIO0 __builtin_amdgcn_s_setprio(0)

// ---------- 256x256-tile GEMM: C[M][N] = A[M][1024] * BT[N][1024]^T ----------
// 512 threads = 8 waves (2Mx4N). BK=64, 16 K-tiles. LDS 128KiB double-buffered.
// Swizzle involution on [128][64]bf16 halves: byte ^= ((byte>>7)&7)<<4.
// Schedule per tile (1 barrier/phase, reads pipelined one phase ahead):
//  ph0: stage A(T+1)x4 | BAR lgkm0 | read B1 | MFMA(0,0)
//  ph1:                | BAR lgkm0 | MFMA(0,1) | read A1
//  ph2:                | BAR lgkm0 | MFMA(1,1)
//  ph3: stage B(T+2)x4, vmcnt(4) | BAR lgkm0 | MFMA(1,0) | read A0,B0 (T+1)
// Region-death ledger: B(T) reads done by ph1-BAR (B(T+2) staged ph3 > safe);
// A(T-1) reads done by ph1(T-1) (A(T+1) staged ph0(T) > safe).
#define READ_A(mq, AO)                                                        \
  {                                                                           \
    _Pragma("unroll") for (int i = 0; i < 4; ++i)                             \
        _Pragma("unroll") for (int kk = 0; kk < 2; ++kk)                      \
            a[i][kk] = *(const bf16x8*)(lds + (AO) +                          \
                                        ((mq)*64 + i * 16 + fr) * 128 +       \
                                        ((kk * 64 + fkb) ^ xo));              \
  }
#define READ_B(nh, BO)                                                        \
  {                                                                           \
    _Pragma("unroll") for (int j = 0; j < 2; ++j)                             \
        _Pragma("unroll") for (int kk = 0; kk < 2; ++kk)                      \
            b[(nh)*2 + j][kk] = *(const bf16x8*)(lds + (BO) +                 \
                                                 (bro + (nh)*32 + j * 16 + fr) * 128 + \
                                                 ((kk * 64 + fkb) ^ xo));     \
  }
#define MFMA_Q(mq, nh)                                                        \
  {                                                                           \
    _Pragma("unroll") for (int i = 0; i < 4; ++i)                             \
        _Pragma("unroll") for (int j = 0; j < 2; ++j) {                       \
      acc[(mq)*4 + i][(nh)*2 + j] = __builtin_amdgcn_mfma_f32_16x16x32_bf16(  \
          a[i][0], b[(nh)*2 + j][0], acc[(mq)*4 + i][(nh)*2 + j], 0, 0, 0);   \
      acc[(mq)*4 + i][(nh)*2 + j] = __builtin_amdgcn_mfma_f32_16x16x32_bf16(  \
          a[i][1], b[(nh)*2 + j][1], acc[(mq)*4 + i][(nh)*2 + j], 0, 0, 0);   \
    }                                                                         \
  }
#define STAGE_A(h, X)                                                         \
  {                                                                           \
    const int ro = ((X)&1) * 65536 + (h)*16384;                               \
    const bf16* g = gA + ((h)*128) * 1024 + (X)*64;                           \
    gload16(g, (bf16*)(lds + ro + wv * 1024));                                \
    gload16(g + 64 * 1024, (bf16*)(lds + ro + 8192 + wv * 1024));             \
  }
#define STAGE_B(h, X)                                                         \
  {                                                                           \
    const int ro = ((X)&1) * 65536 + 32768 + (h)*16384;                       \
    const bf16* g = gB + ((h)*128) * 1024 + (X)*64;                           \
    gload16(g, (bf16*)(lds + ro + wv * 1024));                                \
    gload16(g + 64 * 1024, (bf16*)(lds + ro + 8192 + wv * 1024));             \
  }

template <typename OutT>
__global__ __launch_bounds__(512, 2)
void gemm256(const bf16* __restrict__ A, const bf16* __restrict__ BT,
             OutT* __restrict__ C, int N) {
  constexpr int K = 1024;
  __shared__ __align__(16) char smem[131072];
  char* lds = smem;

  const int tid = threadIdx.x;
  const int lane = tid & 63;
  const int wv = tid >> 6;
  const int wr = wv >> 2;  // 0..1
  const int wc = wv & 3;   // 0..3

  // bijective XCD swizzle, ROW-major tile order (per-XCD A row-panel, B shared)
  const int gx = gridDim.x;
  const int nwg = gx * gridDim.y;
  const int bid = blockIdx.y * gx + blockIdx.x;
  const int swz = (bid & 7) * (nwg >> 3) + (bid >> 3);
  const long row0 = (long)(swz / gx) * 256;
  const long col0 = (long)(swz % gx) * 256;

  // staging source (pre-swizzled so linear global_load_lds dest == swizzled layout)
  const int srow = tid >> 3;  // 0..63
  const int scol = (((tid & 7) * 16) ^ ((srow & 7) << 4)) >> 1;  // elements
  const bf16* gA = A + (row0 + srow) * K + scol;
  const bf16* gB = BT + (col0 + srow) * K + scol;

  // fragment read addressing
  const int fr = lane & 15;
  const int fkb = (lane >> 4) * 16;  // byte offset of k-slice
  const int xo = (fr & 7) << 4;
  const int bro = (wc & 1) * 64;

  bf16x8 a[4][2], b[4][2];
  f32x4 acc[8][4] = {};

  // prologue: tile0 (4 half-tiles) + B(1) (2 half-tiles); keep B(1) in flight
  STAGE_A(0, 0); STAGE_A(1, 0); STAGE_B(0, 0); STAGE_B(1, 0);
  STAGE_B(0, 1); STAGE_B(1, 1);
  asm volatile("s_waitcnt vmcnt(4)" ::: "memory");
  SB(); BAR(); SB();
  {
    const int aoff0 = wr * 16384;
    const int boff0 = 32768 + (wc >> 1) * 16384;
    READ_A(0, aoff0); READ_B(0, boff0);
  }
  SB();

  for (int T = 0; T < 16; ++T) {
    const int d = T & 1;
    const int aoff = d * 65536 + wr * 16384;
    const int boff = d * 65536 + 32768 + (wc >> 1) * 16384;
    const int aoffN = (d ^ 1) * 65536 + wr * 16384;
    const int boffN = (d ^ 1) * 65536 + 32768 + (wc >> 1) * 16384;
    // ph0
    if (T < 15) { STAGE_A(0, T + 1); STAGE_A(1, T + 1); }
    SB(); BAR(); LGKM0; SB();
    READ_B(1, boff); SB();
    PRIO1; MFMA_Q(0, 0); PRIO0; SB();
    // ph1
    BAR(); LGKM0; SB();
    PRIO1; MFMA_Q(0, 1); PRIO0; SB();
    READ_A(1, aoff); SB();
    // ph2
    BAR(); LGKM0; SB();
    PRIO1; MFMA_Q(1, 1); PRIO0; SB();
    // ph3
    if (T < 14) {
      STAGE_B(0, T + 2); STAGE_B(1, T + 2);
      asm volatile("s_waitcnt vmcnt(4)" ::: "memory");
    } else if (T == 14) {
      asm volatile("s_waitcnt vmcnt(0)" ::: "memory");
    }
    SB(); BAR(); LGKM0; SB();
    PRIO1; MFMA_Q(1, 0); PRIO0; SB();
    if (T < 15) { READ_A(0, aoffN); READ_B(0, boffN); }
    SB();
  }

  // epilogue: C/D layout col=lane&15, row=(lane>>4)*4+reg
  const int crow = (lane >> 4) * 4;
  const int ccol = lane & 15;
  const long rb = row0 + wr * 128;
  const long cb = col0 + wc * 64;
#pragma unroll
  for (int m = 0; m < 8; ++m)
#pragma unroll
    for (int n = 0; n < 4; ++n)
#pragma unroll
      for (int i = 0; i < 4; ++i)
        C[(rb + m * 16 + crow + i) * (long)N + cb + n * 16 + ccol] =
            (OutT)acc[m][n][i];
}

// ---------------- fused tiny attention ----------------
__device__ __forceinline__ void load16f(const bf16* p, float* f) {
  const uint4* u = (const uint4*)p;
  uint4 a = u[0], b = u[1];
  uint32_t w[8] = {a.x, a.y, a.z, a.w, b.x, b.y, b.z, b.w};
#pragma unroll
  for (int j = 0; j < 8; ++j) {
    f[2 * j] = __uint_as_float(w[j] << 16);
    f[2 * j + 1] = __uint_as_float(w[j] & 0xffff0000u);
  }
}

// block = (s_hi, g, bz); 256 threads = 16 s_lo x 16 h1
__global__ __launch_bounds__(256)
void attn_fuse(const bf16* __restrict__ qkvw, bf16* __restrict__ ow,
               int b0, long bstride) {
  __shared__ bf16 data[16 * 1024];
  const int s_hi = blockIdx.x;
  const int g = blockIdx.y;
  const int bz = blockIdx.z;
  const int b = b0 + bz;
  const bf16* base = qkvw + (long)bz * bstride;
  const int tid = threadIdx.x;

#pragma unroll
  for (int i = 0; i < 8; ++i) {
    int c = tid + i * 256;
    int h = c >> 7;
    int col = (c & 127) * 8;
    *(uint4*)&data[h * 1024 + col] =
        *(const uint4*)(base + (long)(h * 256 + s_hi) * 4096 + g * 1024 + col);
  }
  __syncthreads();

  const int s_lo = tid >> 4;
  const int h1 = tid & 15;
  const int off = s_lo * 16;

  float q[16], p[16], o[16];
  load16f(&data[h1 * 1024 + off], q);

  float mx = -1e30f;
#pragma unroll
  for (int h2 = 0; h2 < 16; ++h2) {
    float kf[16];
    load16f(&data[h2 * 1024 + 256 + off], kf);
    float s = 0.f;
#pragma unroll
    for (int d = 0; d < 16; ++d) s += q[d] * kf[d];
    s *= 0.25f;  // HD^-0.5, HD=16
    p[h2] = s;
    mx = fmaxf(mx, s);
  }
  float sum = 0.f;
#pragma unroll
  for (int h2 = 0; h2 < 16; ++h2) {
    float e = __expf(p[h2] - mx);
    p[h2] = e;
    sum += e;
  }
  const float inv = 1.f / sum;
#pragma unroll
  for (int d = 0; d < 16; ++d) o[d] = 0.f;
#pragma unroll
  for (int h2 = 0; h2 < 16; ++h2) {
    float vf[16];
    load16f(&data[h2 * 1024 + 512 + off], vf);
    const float av = p[h2] * inv;
#pragma unroll
    for (int d = 0; d < 16; ++d) o[d] += av * vf[d];
  }
  float wf[16];
  load16f(&data[h1 * 1024 + 768 + off], wf);

  const int bp = g * 8 + b;  // concat index along axis 0
  const long R = (long)(bp >> 2) * 4096 + (bp & 3) * 1024 + h1 * 64 + (s_hi >> 2);
  const int cbo = (s_hi & 3) * 256 + off;
  union { uint4 u[2]; bf16 hh[16]; } st;
#pragma unroll
  for (int d = 0; d < 16; ++d) st.hh[d] = (bf16)(o[d] * wf[d]);
  uint4* dst = (uint4*)&ow[R * 1024 + cbo];
  dst[0] = st.u[0];
  dst[1] = st.u[1];
}

// ---------------- casts ----------------
__global__ __launch_bounds__(256)
void cast_x_kernel(const float* __restrict__ in, bf16* __restrict__ out, long n4) {
  long i = (long)blockIdx.x * 256 + threadIdx.x;
  if (i >= n4) return;
  float4 v = ((const float4*)in)[i];
  union { uint2 d; bf16 h[4]; } r;
  r.h[0] = (bf16)v.x; r.h[1] = (bf16)v.y; r.h[2] = (bf16)v.z; r.h[3] = (bf16)v.w;
  ((uint2*)out)[i] = r.d;
}

// out[C][R] = bf16(in[R][C])  (transpose-cast, 64x64 tiles)
__global__ __launch_bounds__(256)
void tcast_kernel(const float* __restrict__ in, bf16* __restrict__ out, int R, int C) {
  __shared__ float t[64][65];
  const int c0 = blockIdx.x * 64, r0 = blockIdx.y * 64;
  const int lr = threadIdx.x >> 6;
  const int lc = threadIdx.x & 63;
#pragma unroll
  for (int i = 0; i < 16; ++i)
    t[lr + i * 4][lc] = in[(long)(r0 + lr + i * 4) * C + c0 + lc];
  __syncthreads();
#pragma unroll
  for (int i = 0; i < 16; ++i) {
    int oc = lr + i * 4;
    out[(long)(c0 + oc) * R + r0 + lc] = (bf16)t[lc][oc];
  }
}

// ---------------- launch ----------------
extern "C" void kernel_launch(void* const* d_in, const int* in_sizes, int n_in,
                              void* d_out, int out_size, void* d_ws, size_t ws_size,
                              hipStream_t stream) {
  const float* x = (const float*)d_in[0];
  const float* w_qkvw = (const float*)d_in[1];
  const float* w_out = (const float*)d_in[2];
  float* out = (float*)d_out;

  char* ws = (char*)d_ws;
  size_t off = 0;
  bf16* x_bf = (bf16*)(ws + off); off += (size_t)32768 * 1024 * 2;
  bf16* bt1  = (bf16*)(ws + off); off += (size_t)4096 * 1024 * 2;
  bf16* bt2  = (bf16*)(ws + off); off += (size_t)1024 * 1024 * 2;
  bf16* owb  = (bf16*)(ws + off); off += (size_t)32768 * 1024 * 2;
  bf16* qk   = (bf16*)(ws + off);
  const size_t rem = ws_size > off ? ws_size - off : 0;
  const size_t full_need = (size_t)32768 * 4096 * 2;

  cast_x_kernel<<<32768, 256, 0, stream>>>(x, x_bf, (long)8388608);
  tcast_kernel<<<dim3(64, 16), 256, 0, stream>>>(w_qkvw, bt1, 1024, 4096);
  tcast_kernel<<<dim3(16, 16), 256, 0, stream>>>(w_out, bt2, 1024, 1024);

  if (rem >= full_need) {
    gemm256<bf16><<<dim3(16, 128), 512, 0, stream>>>(x_bf, bt1, qk, 4096);
    attn_fuse<<<dim3(256, 4, 8), 256, 0, stream>>>(qk, owb, 0, (long)4096 * 4096);
  } else {
    for (int b = 0; b < 8; ++b) {
      gemm256<bf16><<<dim3(16, 16), 512, 0, stream>>>(
          x_bf + (size_t)b * 4096 * 1024, bt1, qk, 4096);
      attn_fuse<<<dim3(256, 4, 1), 256, 0, stream>>>(qk, owb, b, 0);
    }
  }
  gemm256<float><<<dim3(4, 128), 512, 0, stream>>>(owb, bt2, out, 1024);
}

// Round 5
// 458.281 us; speedup vs baseline: 1.1525x; 1.0108x over previous
//
#include <hip/hip_runtime.h>
#include <hip/hip_bf16.h>
#include <stdint.h>

// GroupedQAttention on MI355X.
// cast x->bf16, transpose-cast weights -> bf16 BT,
// GEMM1 (256^2 4-phase, A triple-buffered 160KB LDS, read-pipelined) -> qkvw,
// fused tiny-attention*w -> ow (bf16), GEMM2 (same) -> fp32 out.
// R3 lesson: row-major-ish XCD chunking + plain stores (col-major chunking and
// nontemporal 2B stores both regressed). R5: A 3-buf (issue->need 7 phases),
// 8x4 supertile order per XCD for L2 residency.

typedef __bf16 bf16;
typedef __bf16 bf16x8 __attribute__((ext_vector_type(8)));
typedef float f32x4 __attribute__((ext_vector_type(4)));

__device__ __forceinline__ void gload16(const bf16* g, bf16* l) {
  __builtin_amdgcn_global_load_lds(
      (const __attribute__((address_space(1))) void*)g,
      (__attribute__((address_space(3))) void*)l, 16, 0, 0);
}

#define BAR() asm volatile("s_barrier" ::: "memory")
#define SB() __builtin_amdgcn_sched_barrier(0)
#define LGKM0 asm volatile("s_waitcnt lgkmcnt(0)" ::: "memory")
#define PRIO1 __builtin_amdgcn_s_setprio(1)
#define PRIO0 __builtin_amdgcn_s_setprio(0)

// ---------- 256x256-tile GEMM: C[M][N] = A[M][1024] * BT[N][1024]^T ----------
// 512 threads = 8 waves (2Mx4N). BK=64, 16 K-tiles.
// LDS 160KiB: A buffers 3x32KB at 0/32K/64K (tile T reads buf T%3),
//             B buffers 2x32KB at 96K/128K (tile T reads buf T%2).
// Swizzle involution on [128][64]bf16 halves: byte ^= ((byte>>7)&7)<<4.
// Schedule per tile (1 barrier/phase, reads pipelined one phase ahead):
//  ph0: stage A(T+2)x4 -> buf (T+2)%3 | BAR lgkm0 | read B1 | MFMA(0,0)
//  ph1:                               | BAR lgkm0 | MFMA(0,1) | read A1
//  ph2:                               | BAR lgkm0 | MFMA(1,1)
//  ph3: stage B(T+2)x4, vmcnt(8)      | BAR lgkm0 | MFMA(1,0) | read A0,B0 (T+1)
// Ledger: A(T-1) reads (ph3(T-2) aoffN, ph1(T-1)) drained by ph2(T-1) LGKM0,
//   all-waves via ph3(T-1) BAR < ph0(T) stage into (T+2)%3==(T-1)%3. B(T) reads
//   (ph3(T-1) boffN, ph0(T)) drained by ph1(T) LGKM0, all-waves via ph2(T) BAR
//   < ph3(T) stage into (T+2)%2==T%2. Gate vmcnt(8) at ph3(T) leaves exactly
//   A(T+2)x4+B(T+2)x4 in flight => A(T+1) (dist 7 ph) & B(T+1) (dist 4 ph) landed.
#define READ_A(mq, AO)                                                        \
  {                                                                           \
    _Pragma("unroll") for (int i = 0; i < 4; ++i)                             \
        _Pragma("unroll") for (int kk = 0; kk < 2; ++kk)                      \
            a[i][kk] = *(const bf16x8*)(lds + (AO) +                          \
                                        ((mq)*64 + i * 16 + fr) * 128 +       \
                                        ((kk * 64 + fkb) ^ xo));              \
  }
#define READ_B(nh, BO)                                                        \
  {                                                                           \
    _Pragma("unroll") for (int j = 0; j < 2; ++j)                             \
        _Pragma("unroll") for (int kk = 0; kk < 2; ++kk)                      \
            b[(nh)*2 + j][kk] = *(const bf16x8*)(lds + (BO) +                 \
                                                 (bro + (nh)*32 + j * 16 + fr) * 128 + \
                                                 ((kk * 64 + fkb) ^ xo));     \
  }
#define MFMA_Q(mq, nh)                                                        \
  {                                                                           \
    _Pragma("unroll") for (int i = 0; i < 4; ++i)                             \
        _Pragma("unroll") for (int j = 0; j < 2; ++j) {                       \
      acc[(mq)*4 + i][(nh)*2 + j] = __builtin_amdgcn_mfma_f32_16x16x32_bf16(  \
          a[i][0], b[(nh)*2 + j][0], acc[(mq)*4 + i][(nh)*2 + j], 0, 0, 0);   \
      acc[(mq)*4 + i][(nh)*2 + j] = __builtin_amdgcn_mfma_f32_16x16x32_bf16(  \
          a[i][1], b[(nh)*2 + j][1], acc[(mq)*4 + i][(nh)*2 + j], 0, 0, 0);   \
    }                                                                         \
  }
#define STAGE_AH(h, X, base)                                                  \
  {                                                                           \
    const bf16* g = gA + ((h)*128) * 1024 + (X)*64;                           \
    gload16(g, (bf16*)(lds + (base) + (h)*16384 + wv * 1024));                \
    gload16(g + 64 * 1024, (bf16*)(lds + (base) + (h)*16384 + 8192 + wv * 1024)); \
  }
#define STAGE_BH(h, X)                                                        \
  {                                                                           \
    const int ro = 98304 + ((X)&1) * 32768 + (h)*16384;                       \
    const bf16* g = gB + ((h)*128) * 1024 + (X)*64;                           \
    gload16(g, (bf16*)(lds + ro + wv * 1024));                                \
    gload16(g + 64 * 1024, (bf16*)(lds + ro + 8192 + wv * 1024));             \
  }

template <typename OutT>
__global__ __launch_bounds__(512, 2)
void gemm256(const bf16* __restrict__ A, const bf16* __restrict__ BT,
             OutT* __restrict__ C, int N, int super) {
  constexpr int K = 1024;
  __shared__ __align__(16) char smem[163840];
  char* lds = smem;

  const int tid = threadIdx.x;
  const int lane = tid & 63;
  const int wv = tid >> 6;
  const int wr = wv >> 2;  // 0..1
  const int wc = wv & 3;   // 0..3

  // XCD chunking: per-XCD contiguous range; within it, 8x4 supertiles so the
  // ~32 concurrent blocks/XCD share A row-panels (x4) and B col-panels (x8).
  const int gx = gridDim.x;
  const int nwg = gx * gridDim.y;
  const int bid = blockIdx.y * gx + blockIdx.x;
  const int xcd = bid & 7;
  const int l = bid >> 3;
  long trow, tcol;
  if (super) {  // requires (nwg/8)/gx == 16 and gx%4==0
    const int s = l >> 5, i = l & 31;
    const int colS = gx >> 2;
    trow = xcd * 16 + (s / colS) * 8 + (i >> 2);
    tcol = (s % colS) * 4 + (i & 3);
  } else {
    const int swz = xcd * (nwg >> 3) + l;
    trow = swz / gx;
    tcol = swz % gx;
  }
  const long row0 = trow * 256;
  const long col0 = tcol * 256;

  // staging source (pre-swizzled so linear global_load_lds dest == swizzled layout)
  const int srow = tid >> 3;  // 0..63
  const int scol = (((tid & 7) * 16) ^ ((srow & 7) << 4)) >> 1;  // elements
  const bf16* gA = A + (row0 + srow) * K + scol;
  const bf16* gB = BT + (col0 + srow) * K + scol;

  // fragment read addressing
  const int fr = lane & 15;
  const int fkb = (lane >> 4) * 16;  // byte offset of k-slice
  const int xo = (fr & 7) << 4;
  const int bro = (wc & 1) * 64;

  bf16x8 a[4][2], b[4][2];
  f32x4 acc[8][4] = {};

  // prologue: A(0)->buf0, A(1)->buf1, B(0), B(1); keep B(1) in flight
  STAGE_AH(0, 0, 0); STAGE_AH(1, 0, 0);
  STAGE_AH(0, 1, 32768); STAGE_AH(1, 1, 32768);
  STAGE_BH(0, 0); STAGE_BH(1, 0);
  STAGE_BH(0, 1); STAGE_BH(1, 1);
  asm volatile("s_waitcnt vmcnt(4)" ::: "memory");
  SB(); BAR(); SB();
  READ_A(0, wr * 16384);
  READ_B(0, 98304 + (wc >> 1) * 16384);
  SB();

  int ac0 = 0, ac1 = 32768, ac2 = 65536;  // A bufs: cur, next, stage-target
  for (int T = 0; T < 16; ++T) {
    const int aoff = ac0 + wr * 16384;
    const int aoffN = ac1 + wr * 16384;
    const int boff = 98304 + (T & 1) * 32768 + (wc >> 1) * 16384;
    const int boffN = 98304 + ((T + 1) & 1) * 32768 + (wc >> 1) * 16384;
    // ph0
    if (T < 14) { STAGE_AH(0, T + 2, ac2); STAGE_AH(1, T + 2, ac2); }
    SB(); BAR(); LGKM0; SB();
    READ_B(1, boff); SB();
    PRIO1; MFMA_Q(0, 0); PRIO0; SB();
    // ph1
    BAR(); LGKM0; SB();
    PRIO1; MFMA_Q(0, 1); PRIO0; SB();
    READ_A(1, aoff); SB();
    // ph2
    BAR(); LGKM0; SB();
    PRIO1; MFMA_Q(1, 1); PRIO0; SB();
    // ph3
    if (T < 14) {
      STAGE_BH(0, T + 2); STAGE_BH(1, T + 2);
      asm volatile("s_waitcnt vmcnt(8)" ::: "memory");
    } else if (T == 14) {
      asm volatile("s_waitcnt vmcnt(0)" ::: "memory");
    }
    SB(); BAR(); LGKM0; SB();
    PRIO1; MFMA_Q(1, 0); PRIO0; SB();
    if (T < 15) { READ_A(0, aoffN); READ_B(0, boffN); }
    SB();
    const int t = ac0; ac0 = ac1; ac1 = ac2; ac2 = t;
  }

  // epilogue: C/D layout col=lane&15, row=(lane>>4)*4+reg
  const int crow = (lane >> 4) * 4;
  const int ccol = lane & 15;
  const long rb = row0 + wr * 128;
  const long cb = col0 + wc * 64;
#pragma unroll
  for (int m = 0; m < 8; ++m)
#pragma unroll
    for (int n = 0; n < 4; ++n)
#pragma unroll
      for (int i = 0; i < 4; ++i)
        C[(rb + m * 16 + crow + i) * (long)N + cb + n * 16 + ccol] =
            (OutT)acc[m][n][i];
}

// ---------------- fused tiny attention ----------------
__device__ __forceinline__ void load16f(const bf16* p, float* f) {
  const uint4* u = (const uint4*)p;
  uint4 a = u[0], b = u[1];
  uint32_t w[8] = {a.x, a.y, a.z, a.w, b.x, b.y, b.z, b.w};
#pragma unroll
  for (int j = 0; j < 8; ++j) {
    f[2 * j] = __uint_as_float(w[j] << 16);
    f[2 * j + 1] = __uint_as_float(w[j] & 0xffff0000u);
  }
}

// block = (s_hi, g, bz); 256 threads = 16 s_lo x 16 h1
__global__ __launch_bounds__(256)
void attn_fuse(const bf16* __restrict__ qkvw, bf16* __restrict__ ow,
               int b0, long bstride) {
  __shared__ bf16 data[16 * 1024];
  const int s_hi = blockIdx.x;
  const int g = blockIdx.y;
  const int bz = blockIdx.z;
  const int b = b0 + bz;
  const bf16* base = qkvw + (long)bz * bstride;
  const int tid = threadIdx.x;

#pragma unroll
  for (int i = 0; i < 8; ++i) {
    int c = tid + i * 256;
    int h = c >> 7;
    int col = (c & 127) * 8;
    *(uint4*)&data[h * 1024 + col] =
        *(const uint4*)(base + (long)(h * 256 + s_hi) * 4096 + g * 1024 + col);
  }
  __syncthreads();

  const int s_lo = tid >> 4;
  const int h1 = tid & 15;
  const int off = s_lo * 16;

  float q[16], p[16], o[16];
  load16f(&data[h1 * 1024 + off], q);

  float mx = -1e30f;
#pragma unroll
  for (int h2 = 0; h2 < 16; ++h2) {
    float kf[16];
    load16f(&data[h2 * 1024 + 256 + off], kf);
    float s = 0.f;
#pragma unroll
    for (int d = 0; d < 16; ++d) s += q[d] * kf[d];
    s *= 0.25f;  // HD^-0.5, HD=16
    p[h2] = s;
    mx = fmaxf(mx, s);
  }
  float sum = 0.f;
#pragma unroll
  for (int h2 = 0; h2 < 16; ++h2) {
    float e = __expf(p[h2] - mx);
    p[h2] = e;
    sum += e;
  }
  const float inv = 1.f / sum;
#pragma unroll
  for (int d = 0; d < 16; ++d) o[d] = 0.f;
#pragma unroll
  for (int h2 = 0; h2 < 16; ++h2) {
    float vf[16];
    load16f(&data[h2 * 1024 + 512 + off], vf);
    const float av = p[h2] * inv;
#pragma unroll
    for (int d = 0; d < 16; ++d) o[d] += av * vf[d];
  }
  float wf[16];
  load16f(&data[h1 * 1024 + 768 + off], wf);

  const int bp = g * 8 + b;  // concat index along axis 0
  const long R = (long)(bp >> 2) * 4096 + (bp & 3) * 1024 + h1 * 64 + (s_hi >> 2);
  const int cbo = (s_hi & 3) * 256 + off;
  union { uint4 u[2]; bf16 hh[16]; } st;
#pragma unroll
  for (int d = 0; d < 16; ++d) st.hh[d] = (bf16)(o[d] * wf[d]);
  uint4* dst = (uint4*)&ow[R * 1024 + cbo];
  dst[0] = st.u[0];
  dst[1] = st.u[1];
}

// ---------------- casts ----------------
__global__ __launch_bounds__(256)
void cast_x_kernel(const float* __restrict__ in, bf16* __restrict__ out, long n4) {
  long i = (long)blockIdx.x * 256 + threadIdx.x;
  if (i >= n4) return;
  float4 v = ((const float4*)in)[i];
  union { uint2 d; bf16 h[4]; } r;
  r.h[0] = (bf16)v.x; r.h[1] = (bf16)v.y; r.h[2] = (bf16)v.z; r.h[3] = (bf16)v.w;
  ((uint2*)out)[i] = r.d;
}

// out[C][R] = bf16(in[R][C])  (transpose-cast, 64x64 tiles)
__global__ __launch_bounds__(256)
void tcast_kernel(const float* __restrict__ in, bf16* __restrict__ out, int R, int C) {
  __shared__ float t[64][65];
  const int c0 = blockIdx.x * 64, r0 = blockIdx.y * 64;
  const int lr = threadIdx.x >> 6;
  const int lc = threadIdx.x & 63;
#pragma unroll
  for (int i = 0; i < 16; ++i)
    t[lr + i * 4][lc] = in[(long)(r0 + lr + i * 4) * C + c0 + lc];
  __syncthreads();
#pragma unroll
  for (int i = 0; i < 16; ++i) {
    int oc = lr + i * 4;
    out[(long)(c0 + oc) * R + r0 + lc] = (bf16)t[lc][oc];
  }
}

// ---------------- launch ----------------
extern "C" void kernel_launch(void* const* d_in, const int* in_sizes, int n_in,
                              void* d_out, int out_size, void* d_ws, size_t ws_size,
                              hipStream_t stream) {
  const float* x = (const float*)d_in[0];
  const float* w_qkvw = (const float*)d_in[1];
  const float* w_out = (const float*)d_in[2];
  float* out = (float*)d_out;

  char* ws = (char*)d_ws;
  size_t off = 0;
  bf16* x_bf = (bf16*)(ws + off); off += (size_t)32768 * 1024 * 2;
  bf16* bt1  = (bf16*)(ws + off); off += (size_t)4096 * 1024 * 2;
  bf16* bt2  = (bf16*)(ws + off); off += (size_t)1024 * 1024 * 2;
  bf16* owb  = (bf16*)(ws + off); off += (size_t)32768 * 1024 * 2;
  bf16* qk   = (bf16*)(ws + off);
  const size_t rem = ws_size > off ? ws_size - off : 0;
  const size_t full_need = (size_t)32768 * 4096 * 2;

  cast_x_kernel<<<32768, 256, 0, stream>>>(x, x_bf, (long)8388608);
  tcast_kernel<<<dim3(64, 16), 256, 0, stream>>>(w_qkvw, bt1, 1024, 4096);
  tcast_kernel<<<dim3(16, 16), 256, 0, stream>>>(w_out, bt2, 1024, 1024);

  if (rem >= full_need) {
    gemm256<bf16><<<dim3(16, 128), 512, 0, stream>>>(x_bf, bt1, qk, 4096, 1);
    attn_fuse<<<dim3(256, 4, 8), 256, 0, stream>>>(qk, owb, 0, (long)4096 * 4096);
  } else {
    for (int b = 0; b < 8; ++b) {
      gemm256<bf16><<<dim3(16, 16), 512, 0, stream>>>(
          x_bf + (size_t)b * 4096 * 1024, bt1, qk, 4096, 0);
      attn_fuse<<<dim3(256, 4, 1), 256, 0, stream>>>(qk, owb, b, 0);
    }
  }
  gemm256<float><<<dim3(4, 128), 512, 0, stream>>>(owb, bt2, out, 1024, 1);
}